// Round 1
// baseline (1944.161 us; speedup 1.0000x reference)
//
#include <hip/hip_runtime.h>
#include <cmath>

#define D_ 128
#define H_ 256
#define W_ 256
#define B_ 2
#define NTOT (B_*D_*H_*W_)      // 16,777,216
#define N4   (NTOT/4)
#define NBLK (N4/256)           // 16384 blocks of 256 threads, 4 floats/thread

__device__ __forceinline__ float lk(float x){ return x >= 0.0f ? x : 0.01f*x; }

template<bool MN>
__device__ __forceinline__ float opf(float a, float b){ return MN ? fminf(a,b) : fmaxf(a,b); }

// Direct 3x3x3 min/max pool, stride 1, pad 1 (clipped window == +/-inf pad).
// Each thread produces 4 consecutive W outputs (aligned float4).
template<bool MN>
__global__ __launch_bounds__(256) void pool3(const float* __restrict__ in,
                                             float* __restrict__ out,
                                             const int* __restrict__ gate){
    if (gate && *gate == 0) return;   // frozen: output unused downstream
    int idx4 = blockIdx.x*256 + threadIdx.x;
    int w4   = (idx4 & 63) << 2;      // W/4 = 64
    int rest = idx4 >> 6;             // (b*D+d)*H + h
    int h    = rest & (H_-1);
    int d    = (rest >> 8) & (D_-1);
    int base = rest * W_;
    const float PADV = MN ? __builtin_inff() : -__builtin_inff();
    float m0=PADV, m1=PADV, m2=PADV, m3=PADV;
#pragma unroll
    for (int dd=-1; dd<=1; ++dd){
        int dz = d + dd; if (dz < 0 || dz >= D_) continue;
#pragma unroll
        for (int hh=-1; hh<=1; ++hh){
            int hz = h + hh; if (hz < 0 || hz >= H_) continue;
            int rb = base + dd*(H_*W_) + hh*W_ + w4;
            const float4 a = *(const float4*)(in + rb);
            float lft = (w4 > 0)     ? in[rb-1] : PADV;
            float rgt = (w4+4 < W_)  ? in[rb+4] : PADV;
            m0 = opf<MN>(m0, opf<MN>(lft, opf<MN>(a.x, a.y)));
            m1 = opf<MN>(m1, opf<MN>(a.x, opf<MN>(a.y, a.z)));
            m2 = opf<MN>(m2, opf<MN>(a.y, opf<MN>(a.z, a.w)));
            m3 = opf<MN>(m3, opf<MN>(a.z, opf<MN>(a.w, rgt)));
        }
    }
    float4 o; o.x=m0; o.y=m1; o.z=m2; o.w=m3;
    *(float4*)(out + base + w4) = o;
}

// skel_0 = leaky(img0 - open0)
__global__ __launch_bounds__(256) void skel_init(const float* __restrict__ img,
                                                 const float* __restrict__ opn,
                                                 float* __restrict__ S){
    int i4 = (blockIdx.x*256 + threadIdx.x) * 4;
    float4 a = *(const float4*)(img + i4);
    float4 o = *(const float4*)(opn + i4);
    float4 r;
    r.x = lk(a.x - o.x); r.y = lk(a.y - o.y);
    r.z = lk(a.z - o.z); r.w = lk(a.w - o.w);
    *(float4*)(S + i4) = r;
}

// skel update + |diff| reduction for delta_norm
__global__ __launch_bounds__(256) void update_k(const float* __restrict__ img,
                                                const float* __restrict__ opn,
                                                float* __restrict__ S,
                                                double* __restrict__ sum,
                                                const int* __restrict__ flags,
                                                int iter, float lr){
    if (flags[iter] == 0) return;     // frozen: skel unchanged, sums stay 0
    int i4 = (blockIdx.x*256 + threadIdx.x) * 4;
    float4 a = *(const float4*)(img + i4);
    float4 o = *(const float4*)(opn + i4);
    float4 s = *(const float4*)(S + i4);
    float4 sn;
    double loc = 0.0;
    {
        float dl = lk(a.x - o.x); float up = lk(dl - s.x*dl) * lr; sn.x = s.x + up;
        loc += (double)fabsf(iter == 0 ? sn.x : up);
    }
    {
        float dl = lk(a.y - o.y); float up = lk(dl - s.y*dl) * lr; sn.y = s.y + up;
        loc += (double)fabsf(iter == 0 ? sn.y : up);
    }
    {
        float dl = lk(a.z - o.z); float up = lk(dl - s.z*dl) * lr; sn.z = s.z + up;
        loc += (double)fabsf(iter == 0 ? sn.z : up);
    }
    {
        float dl = lk(a.w - o.w); float up = lk(dl - s.w*dl) * lr; sn.w = s.w + up;
        loc += (double)fabsf(iter == 0 ? sn.w : up);
    }
    *(float4*)(S + i4) = sn;
    // wave64 reduce
    #pragma unroll
    for (int off = 32; off > 0; off >>= 1) loc += __shfl_down(loc, off);
    __shared__ double sm[4];
    int lane = threadIdx.x & 63, wv = threadIdx.x >> 6;
    if (lane == 0) sm[wv] = loc;
    __syncthreads();
    if (threadIdx.x == 0){
        double t = sm[0] + sm[1] + sm[2] + sm[3];
        atomicAdd(sum, t);
    }
}

__global__ void flag_k(const double* __restrict__ sum, int* __restrict__ flags, int iter){
    float mean = (float)(*sum / (double)NTOT);
    flags[iter+1] = (flags[iter] != 0) && (mean >= 1e-4f);
}

__global__ void init_ws(double* __restrict__ sums, int* __restrict__ flags){
    int t = threadIdx.x;
    if (t < 20) sums[t] = 0.0;
    if (t < 21) flags[t] = (t == 0) ? 1 : 0;
}

// out = 1.1f * skel  (dt is provably 0 everywhere -> 1 + 0.2*sigmoid(0) = 1.1f)
__global__ __launch_bounds__(256) void scale_k(float* __restrict__ S){
    int i4 = (blockIdx.x*256 + threadIdx.x) * 4;
    float4 s = *(float4*)(S + i4);
    s.x *= 1.1f; s.y *= 1.1f; s.z *= 1.1f; s.w *= 1.1f;
    *(float4*)(S + i4) = s;
}

extern "C" void kernel_launch(void* const* d_in, const int* in_sizes, int n_in,
                              void* d_out, int out_size, void* d_ws, size_t ws_size,
                              hipStream_t stream){
    const float* img0 = (const float*)d_in[0];
    float* S = (float*)d_out;                      // skel lives in d_out
    char* ws = (char*)d_ws;
    size_t vol = (size_t)NTOT * sizeof(float);     // 67 MB
    float* A = (float*)(ws);
    float* B = (float*)(ws + vol);
    float* C = (float*)(ws + 2*vol);
    double* sums = (double*)(ws + 3*vol);
    int*    flags = (int*)(ws + 3*vol + 32*sizeof(double));

    dim3 blk(256), grd(NBLK);

    hipLaunchKernelGGL(init_ws, dim3(1), dim3(64), 0, stream, sums, flags);

    // init: A = erode(img0) = img_1 ; B = dilate(A) = open(img0) ; S = leaky(img0 - B)
    hipLaunchKernelGGL((pool3<true>),  grd, blk, 0, stream, img0, A, (const int*)nullptr);
    hipLaunchKernelGGL((pool3<false>), grd, blk, 0, stream, A, B, (const int*)nullptr);
    hipLaunchKernelGGL(skel_init, grd, blk, 0, stream, img0, B, S);

    // iter 0: img = img_1 (already in A); open(img_1): erode A->B, dilate B->C
    hipLaunchKernelGGL((pool3<true>),  grd, blk, 0, stream, A, B, (const int*)(flags + 0));
    hipLaunchKernelGGL((pool3<false>), grd, blk, 0, stream, B, C, (const int*)(flags + 0));
    hipLaunchKernelGGL(update_k, grd, blk, 0, stream, A, C, S, sums + 0, (const int*)flags, 0, 0.1f);
    hipLaunchKernelGGL(flag_k, dim3(1), dim3(1), 0, stream, sums + 0, flags, 0);

    float* cur = A; float* n1 = B; float* n2 = C;
    for (int i = 1; i < 20; ++i){
        float lr = (float)(0.1 * pow(0.5, (double)(i / 4)));
        hipLaunchKernelGGL((pool3<true>),  grd, blk, 0, stream, cur, n1, (const int*)(flags + i));
        hipLaunchKernelGGL((pool3<true>),  grd, blk, 0, stream, n1,  n2, (const int*)(flags + i));
        hipLaunchKernelGGL((pool3<false>), grd, blk, 0, stream, n2, cur, (const int*)(flags + i));
        hipLaunchKernelGGL(update_k, grd, blk, 0, stream, n1, cur, S, sums + i, (const int*)flags, i, lr);
        hipLaunchKernelGGL(flag_k, dim3(1), dim3(1), 0, stream, sums + i, flags, i);
        float* t = cur; cur = n1; n1 = n2; n2 = t;
    }

    hipLaunchKernelGGL(scale_k, grd, blk, 0, stream, S);
}

// Round 2
// 575.436 us; speedup vs baseline: 3.3786x; 3.3786x over previous
//
#include <hip/hip_runtime.h>
#include <cmath>

#define D_ 128
#define H_ 256
#define W_ 256
#define NTOT (2*D_*H_*W_)        // 16,777,216
#define N4   (NTOT/4)            // 4,194,304 float4 groups
#define GBLK 2048
#define CHUNKS (N4/(GBLK*256))   // 8 groups per thread

__device__ __forceinline__ float lk(float x){ return x >= 0.0f ? x : 0.01f*x; }

template<bool MN>
__device__ __forceinline__ float opf(float a, float b){ return MN ? fminf(a,b) : fmaxf(a,b); }

template<bool MN>
__device__ __forceinline__ float4 opf4(float4 a, float4 b){
    float4 r; r.x=opf<MN>(a.x,b.x); r.y=opf<MN>(a.y,b.y);
    r.z=opf<MN>(a.z,b.z); r.w=opf<MN>(a.w,b.w); return r;
}

// 3x3x3 min/max pool (stride1, pad1-clipped) for 4 consecutive W outputs.
// Vertical (d,h) reduce first, then horizontal window via cross-lane shifts:
// a wave's 64 lanes cover exactly one W-row (64*4=256), so lane edges == row edges.
template<bool MN>
__device__ __forceinline__ float4 pool333(const float* __restrict__ in, int idx4){
    const float PADV = MN ? __builtin_inff() : -__builtin_inff();
    int w4   = (idx4 & 63) << 2;
    int rest = idx4 >> 6;              // (b*D + d)*H + h
    int h    = rest & (H_-1);
    int d    = (rest >> 8) & (D_-1);   // batch-local d (b folded into base)
    int base = rest * W_ + w4;
    float4 v = {PADV,PADV,PADV,PADV};
#pragma unroll
    for (int dd=-1; dd<=1; ++dd){
        int dz = d + dd; if (dz < 0 || dz >= D_) continue;   // wave-uniform branch
#pragma unroll
        for (int hh=-1; hh<=1; ++hh){
            int hz = h + hh; if (hz < 0 || hz >= H_) continue;
            float4 a = *(const float4*)(in + base + dd*(H_*W_) + hh*W_);
            v = opf4<MN>(v, a);
        }
    }
    int lane = threadIdx.x & 63;
    float lft = __shfl_up(v.w, 1);   if (lane == 0)  lft = PADV;
    float rgt = __shfl_down(v.x, 1); if (lane == 63) rgt = PADV;
    float4 r;
    r.x = opf<MN>(lft, opf<MN>(v.x, v.y));
    r.y = opf<MN>(v.x, opf<MN>(v.y, v.z));
    r.z = opf<MN>(v.y, opf<MN>(v.z, v.w));
    r.w = opf<MN>(v.z, opf<MN>(v.w, rgt));
    return r;
}

template<bool MN>
__global__ __launch_bounds__(256) void pool_k(const float* __restrict__ in,
                                              float* __restrict__ out,
                                              const int* __restrict__ gate){
    if (gate && *gate == 0) return;
    int t = blockIdx.x*256 + threadIdx.x;
#pragma unroll 2
    for (int c = 0; c < CHUNKS; ++c){
        int idx4 = t + c*(GBLK*256);
        float4 r = pool333<MN>(in, idx4);
        *(float4*)(out + (size_t)idx4*4) = r;
    }
}

// S = leaky(img0 - dilate(E)) with the dilate computed inline (E = erode(img0))
__global__ __launch_bounds__(256) void skelinit_k(const float* __restrict__ img,
                                                  const float* __restrict__ E,
                                                  float* __restrict__ S){
    int t = blockIdx.x*256 + threadIdx.x;
#pragma unroll 2
    for (int c = 0; c < CHUNKS; ++c){
        int idx4 = t + c*(GBLK*256);
        float4 o = pool333<false>(E, idx4);
        float4 a = *(const float4*)(img + (size_t)idx4*4);
        float4 r;
        r.x = lk(a.x-o.x); r.y = lk(a.y-o.y); r.z = lk(a.z-o.z); r.w = lk(a.w-o.w);
        *(float4*)(S + (size_t)idx4*4) = r;
    }
}

// skel update with dilate(E) inline; per-block partial sum (NO global atomics).
// img = E_prev (current image), E = erode(img) (carried to next iter as image).
__global__ __launch_bounds__(256) void fupdate_k(const float* __restrict__ img,
                                                 const float* __restrict__ E,
                                                 float* __restrict__ S,
                                                 double* __restrict__ partials,
                                                 const int* __restrict__ flags,
                                                 int iter, float lr){
    if (flags[iter] == 0) return;     // frozen: S unchanged, flag chain handles rest
    int t = blockIdx.x*256 + threadIdx.x;
    double loc = 0.0;
    for (int c = 0; c < CHUNKS; ++c){
        int idx4 = t + c*(GBLK*256);
        float4 o = pool333<false>(E, idx4);
        float4 a = *(const float4*)(img + (size_t)idx4*4);
        float4 s = *(const float4*)(S + (size_t)idx4*4);
        float4 sn; float dl, up;
        dl = lk(a.x-o.x); up = lk(dl - s.x*dl)*lr; sn.x = s.x+up; loc += (double)fabsf(iter==0 ? sn.x : up);
        dl = lk(a.y-o.y); up = lk(dl - s.y*dl)*lr; sn.y = s.y+up; loc += (double)fabsf(iter==0 ? sn.y : up);
        dl = lk(a.z-o.z); up = lk(dl - s.z*dl)*lr; sn.z = s.z+up; loc += (double)fabsf(iter==0 ? sn.z : up);
        dl = lk(a.w-o.w); up = lk(dl - s.w*dl)*lr; sn.w = s.w+up; loc += (double)fabsf(iter==0 ? sn.w : up);
        *(float4*)(S + (size_t)idx4*4) = sn;
    }
#pragma unroll
    for (int off = 32; off; off >>= 1) loc += __shfl_down(loc, off);
    __shared__ double sm[4];
    if ((threadIdx.x & 63) == 0) sm[threadIdx.x >> 6] = loc;
    __syncthreads();
    if (threadIdx.x == 0) partials[blockIdx.x] = sm[0]+sm[1]+sm[2]+sm[3];
}

// one block: sum 2048 partials, compute next flag. Short-circuits when frozen
// (partials may hold poison then — never read).
__global__ __launch_bounds__(1024) void reduceflag_k(const double* __restrict__ partials,
                                                     int* __restrict__ flags, int iter){
    __shared__ double sm[16];
    int t = threadIdx.x;
    if (flags[iter] == 0){ if (t == 0) flags[iter+1] = 0; return; }
    double loc = partials[t] + partials[t + 1024];
#pragma unroll
    for (int off = 32; off; off >>= 1) loc += __shfl_down(loc, off);
    if ((t & 63) == 0) sm[t >> 6] = loc;
    __syncthreads();
    if (t == 0){
        double s = 0.0;
#pragma unroll
        for (int i = 0; i < 16; ++i) s += sm[i];
        float mean = (float)(s / (double)NTOT);
        flags[iter+1] = (mean >= 1e-4f) ? 1 : 0;
    }
}

__global__ void init_ws(int* __restrict__ flags){ flags[0] = 1; }

// dt is provably 0 (stride-1 pool window contains center) -> out = 1.1f * skel
__global__ __launch_bounds__(256) void scale_k(float* __restrict__ S){
    int t = blockIdx.x*256 + threadIdx.x;
#pragma unroll 2
    for (int c = 0; c < CHUNKS; ++c){
        size_t i4 = (size_t)(t + c*(GBLK*256))*4;
        float4 s = *(float4*)(S + i4);
        s.x *= 1.1f; s.y *= 1.1f; s.z *= 1.1f; s.w *= 1.1f;
        *(float4*)(S + i4) = s;
    }
}

extern "C" void kernel_launch(void* const* d_in, const int* in_sizes, int n_in,
                              void* d_out, int out_size, void* d_ws, size_t ws_size,
                              hipStream_t stream){
    const float* img0 = (const float*)d_in[0];
    float* S = (float*)d_out;
    char* ws = (char*)d_ws;
    size_t vol = (size_t)NTOT * sizeof(float);
    float*  bufs[3] = { (float*)ws, (float*)(ws + vol), (float*)(ws + 2*vol) };
    double* partials = (double*)(ws + 3*vol);
    int*    flags    = (int*)(ws + 3*vol + GBLK*sizeof(double));

    dim3 blk(256), grd(GBLK);
    hipLaunchKernelGGL(init_ws, dim3(1), dim3(1), 0, stream, flags);

    // A = erode(img0); S = leaky(img0 - dilate(A))
    hipLaunchKernelGGL((pool_k<true>), grd, blk, 0, stream, img0, bufs[0], (const int*)nullptr);
    hipLaunchKernelGGL(skelinit_k, grd, blk, 0, stream, img0, bufs[0], S);

    // iteration i: img = bufs[i%3] (== erode^{i+1}(img0)); E_new -> bufs[(i+1)%3]
    // carry: erode(img_{i+1}) computed for open_i IS img_{i+2} -> only 1 erode/iter
    for (int i = 0; i < 20; ++i){
        float* cur = bufs[i % 3];
        float* nxt = bufs[(i+1) % 3];
        float lr = (float)(0.1 * ldexp(1.0, -(i/4)));
        hipLaunchKernelGGL((pool_k<true>), grd, blk, 0, stream, cur, nxt, (const int*)(flags + i));
        hipLaunchKernelGGL(fupdate_k, grd, blk, 0, stream, cur, nxt, S, partials, (const int*)flags, i, lr);
        hipLaunchKernelGGL(reduceflag_k, dim3(1), dim3(1024), 0, stream, partials, flags, i);
    }

    hipLaunchKernelGGL(scale_k, grd, blk, 0, stream, S);
}

// Round 3
// 559.186 us; speedup vs baseline: 3.4768x; 1.0291x over previous
//
#include <hip/hip_runtime.h>
#include <cmath>

#define D_ 128
#define H_ 256
#define W_ 256
#define NTOT (2*D_*H_*W_)        // 16,777,216
#define N4   (NTOT/4)
#define STRIPS (H_/16)           // 16 strips of 16 rows
#define GBLK (2*D_*STRIPS)       // 4096 blocks: (b, d, strip); wave w owns 4 rows

__device__ __forceinline__ float lk(float x){ return x >= 0.0f ? x : 0.01f*x; }

template<bool MN>
__device__ __forceinline__ float opf(float a, float b){ return MN ? fminf(a,b) : fmaxf(a,b); }

template<bool MN>
__device__ __forceinline__ float4 opf4(float4 a, float4 b){
    float4 r; r.x=opf<MN>(a.x,b.x); r.y=opf<MN>(a.y,b.y);
    r.z=opf<MN>(a.z,b.z); r.w=opf<MN>(a.w,b.w); return r;
}

// Register-tiled 3x3x3 pool: thread at (b,d,h0..h0+3,w4=lane) computes 4 output
// rows. Separable: depth-min (3 planes) -> vertical (6->4 rows) -> horizontal
// (2 shuffles/row; wave's 64 lanes == one full W row, so lane edges == row edges).
// 18 loads / 4 float4 outputs (vs 9/1 before). res[0..3] = pooled rows h0..h0+3.
template<bool MN>
__device__ __forceinline__ void pool4(const float4* __restrict__ in4,
                                      int b, int d, int h0, int lane,
                                      float4 res[4]){
    const float PADV = MN ? __builtin_inff() : -__builtin_inff();
    const float4 P4 = {PADV,PADV,PADV,PADV};
    float4 pm[6];
#pragma unroll
    for (int j=0;j<6;++j) pm[j] = P4;
#pragma unroll
    for (int pp=0; pp<3; ++pp){
        int p = d-1+pp; if (p < 0 || p >= D_) continue;          // block-uniform
        const float4* pl = in4 + (size_t)(b*D_+p)*H_*64 + lane;
#pragma unroll
        for (int j=0;j<6;++j){
            int hh = h0-1+j; if (hh < 0 || hh >= H_) continue;   // wave-uniform
            pm[j] = opf4<MN>(pm[j], pl[hh*64]);
        }
    }
#pragma unroll
    for (int j=0;j<4;++j){
        float4 v = opf4<MN>(pm[j], opf4<MN>(pm[j+1], pm[j+2]));
        float lft = __shfl_up(v.w, 1);   if (lane == 0)  lft = PADV;
        float rgt = __shfl_down(v.x, 1); if (lane == 63) rgt = PADV;
        res[j].x = opf<MN>(lft, opf<MN>(v.x, v.y));
        res[j].y = opf<MN>(v.x, opf<MN>(v.y, v.z));
        res[j].z = opf<MN>(v.y, opf<MN>(v.z, v.w));
        res[j].w = opf<MN>(v.z, opf<MN>(v.w, rgt));
    }
}

__device__ __forceinline__ void decode(int bi, int lane_wv, int& b, int& d, int& h0){
    int strip = bi & (STRIPS-1);
    d = (bi >> 4) & (D_-1);
    b = bi >> 11;
    h0 = strip*16 + lane_wv*4;
}

template<bool MN>
__global__ __launch_bounds__(256,4) void pool_k(const float* __restrict__ in,
                                                float* __restrict__ out,
                                                const int* __restrict__ gate){
    if (gate && *gate == 0) return;
    int lane = threadIdx.x & 63, wv = threadIdx.x >> 6;
    int b, d, h0; decode(blockIdx.x, wv, b, d, h0);
    float4 res[4];
    pool4<MN>((const float4*)in, b, d, h0, lane, res);
    float4* o4 = (float4*)out + (size_t)(b*D_+d)*H_*64 + lane;
#pragma unroll
    for (int j=0;j<4;++j) o4[(h0+j)*64] = res[j];
}

// S = leaky(img - dilate(E));  E = erode(img)
__global__ __launch_bounds__(256,4) void skelinit_k(const float* __restrict__ img,
                                                    const float* __restrict__ E,
                                                    float* __restrict__ S){
    int lane = threadIdx.x & 63, wv = threadIdx.x >> 6;
    int b, d, h0; decode(blockIdx.x, wv, b, d, h0);
    float4 o[4];
    pool4<false>((const float4*)E, b, d, h0, lane, o);
    const float4* a4 = (const float4*)img + (size_t)(b*D_+d)*H_*64 + lane;
    float4* s4 = (float4*)S + (size_t)(b*D_+d)*H_*64 + lane;
#pragma unroll
    for (int j=0;j<4;++j){
        float4 a = a4[(h0+j)*64];
        float4 r;
        r.x = lk(a.x-o[j].x); r.y = lk(a.y-o[j].y);
        r.z = lk(a.z-o[j].z); r.w = lk(a.w-o[j].w);
        s4[(h0+j)*64] = r;
    }
}

// skel update with dilate(E) inline; per-block partials (no global atomics).
__global__ __launch_bounds__(256,4) void fupdate_k(const float* __restrict__ img,
                                                   const float* __restrict__ E,
                                                   float* __restrict__ S,
                                                   double* __restrict__ partials,
                                                   const int* __restrict__ flags,
                                                   int iter, float lr){
    if (flags[iter] == 0) return;
    int lane = threadIdx.x & 63, wv = threadIdx.x >> 6;
    int b, d, h0; decode(blockIdx.x, wv, b, d, h0);
    float4 o[4];
    pool4<false>((const float4*)E, b, d, h0, lane, o);
    const float4* a4 = (const float4*)img + (size_t)(b*D_+d)*H_*64 + lane;
    float4* s4 = (float4*)S + (size_t)(b*D_+d)*H_*64 + lane;
    double loc = 0.0;
#pragma unroll
    for (int j=0;j<4;++j){
        float4 a = a4[(h0+j)*64];
        float4 s = s4[(h0+j)*64];
        float4 sn; float dl, up;
        dl = lk(a.x-o[j].x); up = lk(dl - s.x*dl)*lr; sn.x = s.x+up; loc += (double)fabsf(iter==0 ? sn.x : up);
        dl = lk(a.y-o[j].y); up = lk(dl - s.y*dl)*lr; sn.y = s.y+up; loc += (double)fabsf(iter==0 ? sn.y : up);
        dl = lk(a.z-o[j].z); up = lk(dl - s.z*dl)*lr; sn.z = s.z+up; loc += (double)fabsf(iter==0 ? sn.z : up);
        dl = lk(a.w-o[j].w); up = lk(dl - s.w*dl)*lr; sn.w = s.w+up; loc += (double)fabsf(iter==0 ? sn.w : up);
        s4[(h0+j)*64] = sn;
    }
#pragma unroll
    for (int off = 32; off; off >>= 1) loc += __shfl_down(loc, off);
    __shared__ double sm[4];
    if (lane == 0) sm[wv] = loc;
    __syncthreads();
    if (threadIdx.x == 0) partials[blockIdx.x] = sm[0]+sm[1]+sm[2]+sm[3];
}

// one block: sum GBLK partials, emit next flag (short-circuit when frozen).
__global__ __launch_bounds__(1024) void reduceflag_k(const double* __restrict__ partials,
                                                     int* __restrict__ flags, int iter){
    __shared__ double sm[16];
    int t = threadIdx.x;
    if (flags[iter] == 0){ if (t == 0) flags[iter+1] = 0; return; }
    double loc = 0.0;
#pragma unroll
    for (int c=0;c<GBLK/1024;++c) loc += partials[t + c*1024];
#pragma unroll
    for (int off = 32; off; off >>= 1) loc += __shfl_down(loc, off);
    if ((t & 63) == 0) sm[t >> 6] = loc;
    __syncthreads();
    if (t == 0){
        double s = 0.0;
#pragma unroll
        for (int i = 0; i < 16; ++i) s += sm[i];
        float mean = (float)(s / (double)NTOT);
        flags[iter+1] = (mean >= 1e-4f) ? 1 : 0;
    }
}

__global__ void init_ws(int* __restrict__ flags){ flags[0] = 1; }

// dt == 0 identically (stride-1 window contains center) -> out = 1.1f * skel
__global__ __launch_bounds__(256) void scale_k(float* __restrict__ S){
    size_t i4 = (size_t)(blockIdx.x*256 + threadIdx.x)*4;
    float4 s = *(float4*)(S + i4);
    s.x *= 1.1f; s.y *= 1.1f; s.z *= 1.1f; s.w *= 1.1f;
    *(float4*)(S + i4) = s;
}

extern "C" void kernel_launch(void* const* d_in, const int* in_sizes, int n_in,
                              void* d_out, int out_size, void* d_ws, size_t ws_size,
                              hipStream_t stream){
    const float* img0 = (const float*)d_in[0];
    float* S = (float*)d_out;
    char* ws = (char*)d_ws;
    size_t vol = (size_t)NTOT * sizeof(float);
    float*  bufs[3] = { (float*)ws, (float*)(ws + vol), (float*)(ws + 2*vol) };
    double* partials = (double*)(ws + 3*vol);
    int*    flags    = (int*)(ws + 3*vol + GBLK*sizeof(double));

    dim3 blk(256), grd(GBLK);
    hipLaunchKernelGGL(init_ws, dim3(1), dim3(1), 0, stream, flags);

    // A = erode(img0); S = leaky(img0 - dilate(A))
    hipLaunchKernelGGL((pool_k<true>), grd, blk, 0, stream, img0, bufs[0], (const int*)nullptr);
    hipLaunchKernelGGL(skelinit_k, grd, blk, 0, stream, img0, bufs[0], S);

    // iter i: img = bufs[i%3] (= erode^{i+1}(img0)); erode(img) -> bufs[(i+1)%3]
    // (that erode, needed for open_i, IS the next iteration's image: 1 pool/iter)
    for (int i = 0; i < 20; ++i){
        float* cur = bufs[i % 3];
        float* nxt = bufs[(i+1) % 3];
        float lr = (float)(0.1 * ldexp(1.0, -(i/4)));
        hipLaunchKernelGGL((pool_k<true>), grd, blk, 0, stream, cur, nxt, (const int*)(flags + i));
        hipLaunchKernelGGL(fupdate_k, grd, blk, 0, stream, cur, nxt, S, partials, (const int*)flags, i, lr);
        hipLaunchKernelGGL(reduceflag_k, dim3(1), dim3(1024), 0, stream, partials, flags, i);
    }

    hipLaunchKernelGGL(scale_k, dim3(N4/256), blk, 0, stream, S);
}